// Round 1
// baseline (35422.345 us; speedup 1.0000x reference)
//
#include <hip/hip_runtime.h>
#include <hip/hip_bf16.h>
#include <math.h>

// ---------------- constants ----------------
#define BATCH 16
#define CIN 3
#define SIMG 512
#define PPATCH 16
#define DMODEL 256
#define HIDDEN 1024
#define LAYERS 8
#define NHEADS 4
#define DHEAD 64
#define NTOK 1025            // 1024 patches + cls
#define NROWS (BATCH * NTOK) // 16400
#define NCLS 1000

// ---------------- RoPE tables ----------------
__global__ void rope_tab_kernel(float* __restrict__ cosb, float* __restrict__ sinb) {
    int i = blockIdx.x * 256 + threadIdx.x;
    if (i >= NTOK * 128) return;
    int n = i >> 7, j = i & 127;
    float inv = powf(10000.0f, -(float)(2 * j) / 256.0f);
    float ang = (float)n * inv;
    cosb[i] = cosf(ang);
    sinb[i] = sinf(ang);
}

// ---------------- cls token broadcast ----------------
__global__ void cls_kernel(const float* __restrict__ cls, float* __restrict__ tok) {
    int i = blockIdx.x * 256 + threadIdx.x; // 16*256
    int b = i >> 8, d = i & 255;
    tok[(size_t)b * NTOK * DMODEL + d] = cls[d];
}

// ---------------- patch embed ----------------
// 8 patches per block (same patch-row), 256 threads (one per output channel d).
#define NPB 8
__global__ __launch_bounds__(256) void patch_embed_kernel(
    const float* __restrict__ x, const float* __restrict__ w,
    const float* __restrict__ cb, float* __restrict__ tok)
{
    __shared__ __align__(16) float xs[CIN * PPATCH * NPB * PPATCH]; // [c][p][u][q] 6144 f
    int blk = blockIdx.x;        // 2048 = 16 * 128
    int b = blk >> 7;
    int pg = blk & 127;
    int ph = pg >> 2;            // patch row (32 rows, 4 groups each)
    int pw0 = (pg & 3) * NPB;
    int tid = threadIdx.x;
    for (int i4 = tid; i4 < 1536; i4 += 256) {
        int i = i4 * 4;
        int q = i & 15, u = (i >> 4) & 7, p = (i >> 7) & 15, c = i >> 11;
        const float* src = x + (((size_t)(b * CIN + c) * SIMG) + ph * PPATCH + p) * SIMG
                             + (pw0 + u) * PPATCH + q;
        *(float4*)&xs[i] = *(const float4*)src;
    }
    __syncthreads();
    int d = tid;
    const float* wr = w + (size_t)d * 768;
    float acc[NPB] = {};
    for (int cp = 0; cp < 48; ++cp) {
        #pragma unroll
        for (int q4 = 0; q4 < 4; ++q4) {
            float4 wv = *(const float4*)(wr + cp * 16 + q4 * 4);
            #pragma unroll
            for (int u = 0; u < NPB; ++u) {
                float4 xv = *(const float4*)&xs[(cp * 8 + u) * 16 + q4 * 4];
                acc[u] += wv.x * xv.x + wv.y * xv.y + wv.z * xv.z + wv.w * xv.w;
            }
        }
    }
    float bd = cb[d];
    for (int u = 0; u < NPB; ++u) {
        int pi = ph * 32 + pw0 + u;
        tok[((size_t)b * NTOK + 1 + pi) * DMODEL + d] = acc[u] + bd;
    }
}

// ---------------- layernorm: one wave per 256-wide row ----------------
__global__ __launch_bounds__(256) void ln_kernel(
    const float* __restrict__ in, float* __restrict__ out,
    const float* __restrict__ g, const float* __restrict__ bta,
    int nrows, long in_stride, long out_stride)
{
    int row = blockIdx.x * 4 + (threadIdx.x >> 6);
    int lane = threadIdx.x & 63;
    if (row >= nrows) return;
    const float* xr = in + (size_t)row * in_stride;
    float4 v = *(const float4*)(xr + lane * 4);
    float s = v.x + v.y + v.z + v.w;
    float ss = v.x * v.x + v.y * v.y + v.z * v.z + v.w * v.w;
    #pragma unroll
    for (int m = 1; m < 64; m <<= 1) {
        s += __shfl_xor(s, m, 64);
        ss += __shfl_xor(ss, m, 64);
    }
    float mean = s * (1.0f / 256.0f);
    float var = ss * (1.0f / 256.0f) - mean * mean;
    float inv = rsqrtf(var + 1e-5f);
    float4 gv = *(const float4*)(g + lane * 4);
    float4 bv = *(const float4*)(bta + lane * 4);
    float4 o;
    o.x = (v.x - mean) * inv * gv.x + bv.x;
    o.y = (v.y - mean) * inv * gv.y + bv.y;
    o.z = (v.z - mean) * inv * gv.z + bv.z;
    o.w = (v.w - mean) * inv * gv.w + bv.w;
    *(float4*)(out + (size_t)row * out_stride + lane * 4) = o;
}

// ---------------- tiled fp32 GEMM with epilogues ----------------
// C[M,Nn] = A[M,K] @ W[K,Nn] (+bias, +rope, +residual, +gelu)
enum { EPI_BIAS = 0, EPI_ROPE = 1, EPI_RES = 2, EPI_GELU = 3 };

template <int EPI>
__global__ __launch_bounds__(256) void gemm_ep_kernel(
    const float* __restrict__ A, const float* __restrict__ W,
    const float* __restrict__ bias, float* __restrict__ C,
    const float* __restrict__ cosb, const float* __restrict__ sinb,
    int M, int K, int Nn)
{
    __shared__ __align__(16) float As[16][68];
    __shared__ __align__(16) float Bs[16][68];
    int tid = threadIdx.x;
    int m0 = blockIdx.y * 64;
    int n0 = blockIdx.x * 64;
    int tx = tid & 15, ty = tid >> 4;
    int a_m = tid >> 2, a_k = (tid & 3) * 4;
    int b_k = tid >> 4, b_n = (tid & 15) * 4;
    float acc[4][4] = {};
    for (int k0 = 0; k0 < K; k0 += 16) {
        float4 av = make_float4(0.f, 0.f, 0.f, 0.f);
        int arow = m0 + a_m;
        if (arow < M) av = *(const float4*)(A + (size_t)arow * K + k0 + a_k);
        As[a_k + 0][a_m] = av.x;
        As[a_k + 1][a_m] = av.y;
        As[a_k + 2][a_m] = av.z;
        As[a_k + 3][a_m] = av.w;
        float4 bv = *(const float4*)(W + (size_t)(k0 + b_k) * Nn + n0 + b_n);
        *(float4*)&Bs[b_k][b_n] = bv;
        __syncthreads();
        #pragma unroll
        for (int kk = 0; kk < 16; ++kk) {
            float4 a4 = *(const float4*)&As[kk][ty * 4];
            float4 b4 = *(const float4*)&Bs[kk][tx * 4];
            float ar[4] = {a4.x, a4.y, a4.z, a4.w};
            float br[4] = {b4.x, b4.y, b4.z, b4.w};
            #pragma unroll
            for (int i = 0; i < 4; ++i)
                #pragma unroll
                for (int j = 0; j < 4; ++j)
                    acc[i][j] += ar[i] * br[j];
        }
        __syncthreads();
    }
    int col = n0 + tx * 4;
    float4 bb = *(const float4*)(bias + col);
    #pragma unroll
    for (int i = 0; i < 4; ++i) {
        int row = m0 + ty * 4 + i;
        if (row >= M) break;
        float v0 = acc[i][0] + bb.x;
        float v1 = acc[i][1] + bb.y;
        float v2 = acc[i][2] + bb.z;
        float v3 = acc[i][3] + bb.w;
        float4 o;
        if (EPI == EPI_ROPE) {
            int tokn = row % NTOK;
            const float* cr = cosb + tokn * 128;
            const float* sr = sinb + tokn * 128;
            int jp = col >> 1;
            float c0 = cr[jp], s0 = sr[jp], c1 = cr[jp + 1], s1 = sr[jp + 1];
            o.x = v0 * c0 - v1 * s0;
            o.y = v0 * s0 + v1 * c0;
            o.z = v2 * c1 - v3 * s1;
            o.w = v2 * s1 + v3 * c1;
        } else if (EPI == EPI_GELU) {
            o.x = 0.5f * v0 * (1.0f + erff(v0 * 0.70710678118f));
            o.y = 0.5f * v1 * (1.0f + erff(v1 * 0.70710678118f));
            o.z = 0.5f * v2 * (1.0f + erff(v2 * 0.70710678118f));
            o.w = 0.5f * v3 * (1.0f + erff(v3 * 0.70710678118f));
        } else if (EPI == EPI_RES) {
            float4 rv = *(const float4*)(C + (size_t)row * Nn + col);
            o.x = v0 + rv.x; o.y = v1 + rv.y; o.z = v2 + rv.z; o.w = v3 + rv.w;
        } else {
            o.x = v0; o.y = v1; o.z = v2; o.w = v3;
        }
        *(float4*)(C + (size_t)row * Nn + col) = o;
    }
}

// ---------------- attention: one block per (b, head, q-row) ----------------
__global__ __launch_bounds__(256) void attn_kernel(
    const float* __restrict__ Q, const float* __restrict__ K,
    const float* __restrict__ V, float* __restrict__ O)
{
    __shared__ float sc[NTOK];
    __shared__ float qv[DHEAD];
    __shared__ float red[8];
    __shared__ float part[4][DHEAD];
    int bid = blockIdx.x;
    int qi = bid % NTOK;
    int hh = (bid / NTOK) & 3;
    int b = bid / (NTOK * NHEADS);
    int tid = threadIdx.x;
    size_t base = (size_t)b * NTOK * DMODEL + hh * DHEAD;
    if (tid < DHEAD) qv[tid] = Q[base + (size_t)qi * DMODEL + tid];
    __syncthreads();
    for (int k = tid; k < NTOK; k += 256) {
        const float* kr = K + base + (size_t)k * DMODEL;
        float dot = 0.f;
        #pragma unroll
        for (int t = 0; t < 16; ++t) {
            float4 k4 = *(const float4*)(kr + t * 4);
            float4 q4 = *(const float4*)&qv[t * 4];
            dot += q4.x * k4.x + q4.y * k4.y + q4.z * k4.z + q4.w * k4.w;
        }
        sc[k] = dot * 0.125f;
    }
    __syncthreads();
    float m = -1e30f;
    for (int k = tid; k < NTOK; k += 256) m = fmaxf(m, sc[k]);
    #pragma unroll
    for (int s = 1; s < 64; s <<= 1) m = fmaxf(m, __shfl_xor(m, s, 64));
    if ((tid & 63) == 0) red[tid >> 6] = m;
    __syncthreads();
    m = fmaxf(fmaxf(red[0], red[1]), fmaxf(red[2], red[3]));
    float lsum = 0.f;
    for (int k = tid; k < NTOK; k += 256) {
        float e = expf(sc[k] - m);
        sc[k] = e;
        lsum += e;
    }
    #pragma unroll
    for (int s = 1; s < 64; s <<= 1) lsum += __shfl_xor(lsum, s, 64);
    if ((tid & 63) == 0) red[4 + (tid >> 6)] = lsum;
    __syncthreads();
    float total = red[4] + red[5] + red[6] + red[7];
    int d = tid & 63, ch = tid >> 6;
    float acc = 0.f;
    for (int k = ch; k < NTOK; k += 4)
        acc += sc[k] * V[base + (size_t)k * DMODEL + d];
    part[ch][d] = acc;
    __syncthreads();
    if (tid < DHEAD) {
        float r = (part[0][tid] + part[1][tid] + part[2][tid] + part[3][tid]) / total;
        O[base + (size_t)qi * DMODEL + tid] = r;
    }
}

// ---------------- classifier head ----------------
__global__ void head_kernel(const float* __restrict__ clsl,
                            const float* __restrict__ hw,
                            const float* __restrict__ hb,
                            float* __restrict__ out)
{
    int i = blockIdx.x * 256 + threadIdx.x;
    if (i >= BATCH * NCLS) return;
    int b = i / NCLS, c = i % NCLS;
    const float* xr = clsl + b * DMODEL;
    float acc = hb[c];
    for (int t = 0; t < DMODEL; ++t) acc += xr[t] * hw[t * NCLS + c];
    out[i] = acc;
}

// ---------------- launch ----------------
extern "C" void kernel_launch(void* const* d_in, const int* in_sizes, int n_in,
                              void* d_out, int out_size, void* d_ws, size_t ws_size,
                              hipStream_t stream) {
    const float* x      = (const float*)d_in[0];
    const float* conv_w = (const float*)d_in[1];
    const float* conv_b = (const float*)d_in[2];
    const float* cls_tok= (const float*)d_in[3];
    const float* ln1_g  = (const float*)d_in[4];
    const float* ln1_b  = (const float*)d_in[5];
    const float* wq     = (const float*)d_in[6];
    const float* bq     = (const float*)d_in[7];
    const float* wk     = (const float*)d_in[8];
    const float* bk     = (const float*)d_in[9];
    const float* wv     = (const float*)d_in[10];
    const float* bv     = (const float*)d_in[11];
    const float* wo     = (const float*)d_in[12];
    const float* bo     = (const float*)d_in[13];
    const float* ln2_g  = (const float*)d_in[14];
    const float* ln2_b  = (const float*)d_in[15];
    const float* w1     = (const float*)d_in[16];
    const float* b1     = (const float*)d_in[17];
    const float* w2     = (const float*)d_in[18];
    const float* b2     = (const float*)d_in[19];
    const float* lnf_g  = (const float*)d_in[20];
    const float* lnf_b  = (const float*)d_in[21];
    const float* head_w = (const float*)d_in[22];
    const float* head_b = (const float*)d_in[23];

    float* ws = (float*)d_ws;
    const size_t TOKSZ = (size_t)NROWS * DMODEL; // 4,198,400
    float* h    = ws;
    float* y    = h + TOKSZ;      // also reused as ctx
    float* q    = y + TOKSZ;
    float* k    = q + TOKSZ;
    float* v    = k + TOKSZ;
    float* hid  = v + TOKSZ;      // NROWS * HIDDEN
    float* cosb = hid + (size_t)NROWS * HIDDEN;
    float* sinb = cosb + (size_t)NTOK * 128;
    float* clsl = sinb + (size_t)NTOK * 128;

    rope_tab_kernel<<<(NTOK * 128 + 255) / 256, 256, 0, stream>>>(cosb, sinb);
    cls_kernel<<<BATCH, 256, 0, stream>>>(cls_tok, h);
    patch_embed_kernel<<<BATCH * 128, 256, 0, stream>>>(x, conv_w, conv_b, h);

    const int M = NROWS;
    dim3 g256(DMODEL / 64, (M + 63) / 64);
    dim3 g1024(HIDDEN / 64, (M + 63) / 64);
    int lnGrid = (M + 3) / 4;

    for (int l = 0; l < LAYERS; ++l) {
        const float* Wq = wq + (size_t)l * DMODEL * DMODEL;
        const float* Wk = wk + (size_t)l * DMODEL * DMODEL;
        const float* Wv = wv + (size_t)l * DMODEL * DMODEL;
        const float* Wo = wo + (size_t)l * DMODEL * DMODEL;
        const float* W1 = w1 + (size_t)l * DMODEL * HIDDEN;
        const float* W2 = w2 + (size_t)l * HIDDEN * DMODEL;

        ln_kernel<<<lnGrid, 256, 0, stream>>>(h, y, ln1_g + l * DMODEL, ln1_b + l * DMODEL,
                                              M, DMODEL, DMODEL);
        gemm_ep_kernel<EPI_ROPE><<<g256, 256, 0, stream>>>(
            y, Wq, bq + l * DMODEL, q, cosb, sinb, M, DMODEL, DMODEL);
        gemm_ep_kernel<EPI_ROPE><<<g256, 256, 0, stream>>>(
            y, Wk, bk + l * DMODEL, k, cosb, sinb, M, DMODEL, DMODEL);
        gemm_ep_kernel<EPI_BIAS><<<g256, 256, 0, stream>>>(
            y, Wv, bv + l * DMODEL, v, nullptr, nullptr, M, DMODEL, DMODEL);
        attn_kernel<<<BATCH * NHEADS * NTOK, 256, 0, stream>>>(q, k, v, y);
        gemm_ep_kernel<EPI_RES><<<g256, 256, 0, stream>>>(
            y, Wo, bo + l * DMODEL, h, nullptr, nullptr, M, DMODEL, DMODEL);
        ln_kernel<<<lnGrid, 256, 0, stream>>>(h, y, ln2_g + l * DMODEL, ln2_b + l * DMODEL,
                                              M, DMODEL, DMODEL);
        gemm_ep_kernel<EPI_GELU><<<g1024, 256, 0, stream>>>(
            y, W1, b1 + l * HIDDEN, hid, nullptr, nullptr, M, DMODEL, HIDDEN);
        gemm_ep_kernel<EPI_RES><<<g256, 256, 0, stream>>>(
            hid, W2, b2 + l * DMODEL, h, nullptr, nullptr, M, HIDDEN, DMODEL);
    }
    // final LN on cls rows only
    ln_kernel<<<(BATCH + 3) / 4, 256, 0, stream>>>(h, clsl, lnf_g, lnf_b,
                                                   BATCH, (long)NTOK * DMODEL, DMODEL);
    head_kernel<<<(BATCH * NCLS + 255) / 256, 256, 0, stream>>>(clsl, head_w, head_b,
                                                                (float*)d_out);
}

// Round 2
// 6151.830 us; speedup vs baseline: 5.7580x; 5.7580x over previous
//
#include <hip/hip_runtime.h>
#include <hip/hip_bf16.h>
#include <math.h>

// ---------------- constants ----------------
#define BATCH 16
#define CIN 3
#define SIMG 512
#define PPATCH 16
#define DMODEL 256
#define HIDDEN 1024
#define LAYERS 8
#define NHEADS 4
#define DHEAD 64
#define NTOK 1025            // 1024 patches + cls
#define NROWS (BATCH * NTOK) // 16400
#define NCLS 1000

// ---------------- RoPE tables ----------------
__global__ void rope_tab_kernel(float* __restrict__ cosb, float* __restrict__ sinb) {
    int i = blockIdx.x * 256 + threadIdx.x;
    if (i >= NTOK * 128) return;
    int n = i >> 7, j = i & 127;
    float inv = powf(10000.0f, -(float)(2 * j) / 256.0f);
    float ang = (float)n * inv;
    cosb[i] = cosf(ang);
    sinb[i] = sinf(ang);
}

// ---------------- cls token broadcast ----------------
__global__ void cls_kernel(const float* __restrict__ cls, float* __restrict__ tok) {
    int i = blockIdx.x * 256 + threadIdx.x; // 16*256
    int b = i >> 8, d = i & 255;
    tok[(size_t)b * NTOK * DMODEL + d] = cls[d];
}

// ---------------- patch embed ----------------
#define NPB 8
__global__ __launch_bounds__(256) void patch_embed_kernel(
    const float* __restrict__ x, const float* __restrict__ w,
    const float* __restrict__ cb, float* __restrict__ tok)
{
    __shared__ __align__(16) float xs[CIN * PPATCH * NPB * PPATCH]; // [c][p][u][q]
    int blk = blockIdx.x;        // 2048 = 16 * 128
    int b = blk >> 7;
    int pg = blk & 127;
    int ph = pg >> 2;
    int pw0 = (pg & 3) * NPB;
    int tid = threadIdx.x;
    for (int i4 = tid; i4 < 1536; i4 += 256) {
        int i = i4 * 4;
        int q = i & 15, u = (i >> 4) & 7, p = (i >> 7) & 15, c = i >> 11;
        const float* src = x + (((size_t)(b * CIN + c) * SIMG) + ph * PPATCH + p) * SIMG
                             + (pw0 + u) * PPATCH + q;
        *(float4*)&xs[i] = *(const float4*)src;
    }
    __syncthreads();
    int d = tid;
    const float* wr = w + (size_t)d * 768;
    float acc[NPB] = {};
    for (int cp = 0; cp < 48; ++cp) {
        #pragma unroll
        for (int q4 = 0; q4 < 4; ++q4) {
            float4 wv = *(const float4*)(wr + cp * 16 + q4 * 4);
            #pragma unroll
            for (int u = 0; u < NPB; ++u) {
                float4 xv = *(const float4*)&xs[(cp * 8 + u) * 16 + q4 * 4];
                acc[u] += wv.x * xv.x + wv.y * xv.y + wv.z * xv.z + wv.w * xv.w;
            }
        }
    }
    float bd = cb[d];
    for (int u = 0; u < NPB; ++u) {
        int pi = ph * 32 + pw0 + u;
        tok[((size_t)b * NTOK + 1 + pi) * DMODEL + d] = acc[u] + bd;
    }
}

// ---------------- layernorm: one wave per 256-wide row ----------------
__global__ __launch_bounds__(256) void ln_kernel(
    const float* __restrict__ in, float* __restrict__ out,
    const float* __restrict__ g, const float* __restrict__ bta,
    int nrows, long in_stride, long out_stride)
{
    int row = blockIdx.x * 4 + (threadIdx.x >> 6);
    int lane = threadIdx.x & 63;
    if (row >= nrows) return;
    const float* xr = in + (size_t)row * in_stride;
    float4 v = *(const float4*)(xr + lane * 4);
    float s = v.x + v.y + v.z + v.w;
    float ss = v.x * v.x + v.y * v.y + v.z * v.z + v.w * v.w;
    #pragma unroll
    for (int m = 1; m < 64; m <<= 1) {
        s += __shfl_xor(s, m, 64);
        ss += __shfl_xor(ss, m, 64);
    }
    float mean = s * (1.0f / 256.0f);
    float var = ss * (1.0f / 256.0f) - mean * mean;
    float inv = rsqrtf(var + 1e-5f);
    float4 gv = *(const float4*)(g + lane * 4);
    float4 bv = *(const float4*)(bta + lane * 4);
    float4 o;
    o.x = (v.x - mean) * inv * gv.x + bv.x;
    o.y = (v.y - mean) * inv * gv.y + bv.y;
    o.z = (v.z - mean) * inv * gv.z + bv.z;
    o.w = (v.w - mean) * inv * gv.w + bv.w;
    *(float4*)(out + (size_t)row * out_stride + lane * 4) = o;
}

// ---------------- tiled fp32 GEMM with epilogues ----------------
enum { EPI_BIAS = 0, EPI_ROPE = 1, EPI_RES = 2, EPI_GELU = 3 };

template <int EPI>
__global__ __launch_bounds__(256) void gemm_ep_kernel(
    const float* __restrict__ A, const float* __restrict__ W,
    const float* __restrict__ bias, float* __restrict__ C,
    const float* __restrict__ cosb, const float* __restrict__ sinb,
    int M, int K, int Nn)
{
    __shared__ __align__(16) float As[16][68];
    __shared__ __align__(16) float Bs[16][68];
    int tid = threadIdx.x;
    int m0 = blockIdx.y * 64;
    int n0 = blockIdx.x * 64;
    int tx = tid & 15, ty = tid >> 4;
    int a_m = tid >> 2, a_k = (tid & 3) * 4;
    int b_k = tid >> 4, b_n = (tid & 15) * 4;
    float acc[4][4] = {};
    for (int k0 = 0; k0 < K; k0 += 16) {
        float4 av = make_float4(0.f, 0.f, 0.f, 0.f);
        int arow = m0 + a_m;
        if (arow < M) av = *(const float4*)(A + (size_t)arow * K + k0 + a_k);
        As[a_k + 0][a_m] = av.x;
        As[a_k + 1][a_m] = av.y;
        As[a_k + 2][a_m] = av.z;
        As[a_k + 3][a_m] = av.w;
        float4 bv = *(const float4*)(W + (size_t)(k0 + b_k) * Nn + n0 + b_n);
        *(float4*)&Bs[b_k][b_n] = bv;
        __syncthreads();
        #pragma unroll
        for (int kk = 0; kk < 16; ++kk) {
            float4 a4 = *(const float4*)&As[kk][ty * 4];
            float4 b4 = *(const float4*)&Bs[kk][tx * 4];
            float ar[4] = {a4.x, a4.y, a4.z, a4.w};
            float br[4] = {b4.x, b4.y, b4.z, b4.w};
            #pragma unroll
            for (int i = 0; i < 4; ++i)
                #pragma unroll
                for (int j = 0; j < 4; ++j)
                    acc[i][j] += ar[i] * br[j];
        }
        __syncthreads();
    }
    int col = n0 + tx * 4;
    float4 bb = *(const float4*)(bias + col);
    #pragma unroll
    for (int i = 0; i < 4; ++i) {
        int row = m0 + ty * 4 + i;
        if (row >= M) break;
        float v0 = acc[i][0] + bb.x;
        float v1 = acc[i][1] + bb.y;
        float v2 = acc[i][2] + bb.z;
        float v3 = acc[i][3] + bb.w;
        float4 o;
        if (EPI == EPI_ROPE) {
            int tokn = row % NTOK;
            const float* cr = cosb + tokn * 128;
            const float* sr = sinb + tokn * 128;
            int jp = col >> 1;
            float c0 = cr[jp], s0 = sr[jp], c1 = cr[jp + 1], s1 = sr[jp + 1];
            o.x = v0 * c0 - v1 * s0;
            o.y = v0 * s0 + v1 * c0;
            o.z = v2 * c1 - v3 * s1;
            o.w = v2 * s1 + v3 * c1;
        } else if (EPI == EPI_GELU) {
            o.x = 0.5f * v0 * (1.0f + erff(v0 * 0.70710678118f));
            o.y = 0.5f * v1 * (1.0f + erff(v1 * 0.70710678118f));
            o.z = 0.5f * v2 * (1.0f + erff(v2 * 0.70710678118f));
            o.w = 0.5f * v3 * (1.0f + erff(v3 * 0.70710678118f));
        } else if (EPI == EPI_RES) {
            float4 rv = *(const float4*)(C + (size_t)row * Nn + col);
            o.x = v0 + rv.x; o.y = v1 + rv.y; o.z = v2 + rv.z; o.w = v3 + rv.w;
        } else {
            o.x = v0; o.y = v1; o.z = v2; o.w = v3;
        }
        *(float4*)(C + (size_t)row * Nn + col) = o;
    }
}

// ---------------- flash attention: 64 queries x one (b,h) per block ----------------
// LDS: Qt (Q^T, [k][qrow]), KtPs (K^T [k][kcol], aliased as P [qrow][k]),
//      Vs ([krow][c]). All stride-68 (2-way conflict-free like gemm_ep).
__global__ __launch_bounds__(256) void flash_attn_kernel(
    const float* __restrict__ Q, const float* __restrict__ K,
    const float* __restrict__ V, float* __restrict__ O)
{
    __shared__ __align__(16) float Qt[64][68];
    __shared__ __align__(16) float KtPs[64][68];
    __shared__ __align__(16) float Vs[64][68];

    int tid = threadIdx.x;
    int tx = tid & 15, ty = tid >> 4;
    int bh = blockIdx.y;
    int b = bh >> 2, h = bh & 3;
    int q0 = blockIdx.x * 64;
    size_t base = (size_t)b * NTOK * DMODEL + (size_t)h * DHEAD;

    // stage Q^T once
    {
        int r = tid >> 2, c4 = tid & 3;
        int qr = q0 + r; if (qr > NTOK - 1) qr = NTOK - 1;
        const float* src = Q + base + (size_t)qr * DMODEL;
        #pragma unroll
        for (int e = 0; e < 4; ++e) {
            int c = (c4 * 4 + e) * 4;
            float4 v = *(const float4*)(src + c);
            Qt[c + 0][r] = v.x; Qt[c + 1][r] = v.y;
            Qt[c + 2][r] = v.z; Qt[c + 3][r] = v.w;
        }
    }

    float m_run[4] = {-1e30f, -1e30f, -1e30f, -1e30f};
    float l_run[4] = {0.f, 0.f, 0.f, 0.f};
    float acc[4][4] = {};

    for (int kt = 0; kt < 17; ++kt) {
        __syncthreads();  // prev-iter LDS reads done (covers Qt staging on iter 0)
        // stage K^T and V tile
        {
            int r = tid >> 2, c4 = tid & 3;
            int kr = kt * 64 + r; if (kr > NTOK - 1) kr = NTOK - 1;
            const float* ksrc = K + base + (size_t)kr * DMODEL;
            const float* vsrc = V + base + (size_t)kr * DMODEL;
            #pragma unroll
            for (int e = 0; e < 4; ++e) {
                int c = (c4 * 4 + e) * 4;
                float4 kv = *(const float4*)(ksrc + c);
                KtPs[c + 0][r] = kv.x; KtPs[c + 1][r] = kv.y;
                KtPs[c + 2][r] = kv.z; KtPs[c + 3][r] = kv.w;
                *(float4*)&Vs[r][c] = *(const float4*)(vsrc + c);
            }
        }
        __syncthreads();

        // S tile: s[i][j] = sum_k Qt[k][4ty+i] * Kt[k][4tx+j]
        float s[4][4] = {};
        #pragma unroll 8
        for (int k = 0; k < 64; ++k) {
            float4 qv = *(const float4*)&Qt[k][ty * 4];
            float4 kv = *(const float4*)&KtPs[k][tx * 4];
            float qa[4] = {qv.x, qv.y, qv.z, qv.w};
            float ka[4] = {kv.x, kv.y, kv.z, kv.w};
            #pragma unroll
            for (int i = 0; i < 4; ++i)
                #pragma unroll
                for (int j = 0; j < 4; ++j)
                    s[i][j] += qa[i] * ka[j];
        }

        // online softmax (per row 4ty+i; 16 tx lanes hold the 64 cols)
        int kbase = kt * 64 + tx * 4;
        #pragma unroll
        for (int i = 0; i < 4; ++i) {
            #pragma unroll
            for (int j = 0; j < 4; ++j) {
                s[i][j] *= 0.125f;
                if (kbase + j >= NTOK) s[i][j] = -1e30f;
            }
            float rm = fmaxf(fmaxf(s[i][0], s[i][1]), fmaxf(s[i][2], s[i][3]));
            #pragma unroll
            for (int t = 1; t < 16; t <<= 1) rm = fmaxf(rm, __shfl_xor(rm, t, 16));
            float mn = fmaxf(m_run[i], rm);
            float sc = __expf(m_run[i] - mn);
            float rs = 0.f;
            #pragma unroll
            for (int j = 0; j < 4; ++j) { s[i][j] = __expf(s[i][j] - mn); rs += s[i][j]; }
            #pragma unroll
            for (int t = 1; t < 16; t <<= 1) rs += __shfl_xor(rs, t, 16);
            l_run[i] = l_run[i] * sc + rs;
            m_run[i] = mn;
            #pragma unroll
            for (int j = 0; j < 4; ++j) acc[i][j] *= sc;
        }

        __syncthreads();  // all Kt reads done -> safe to overwrite as P
        #pragma unroll
        for (int i = 0; i < 4; ++i)
            *(float4*)&KtPs[ty * 4 + i][tx * 4] =
                make_float4(s[i][0], s[i][1], s[i][2], s[i][3]);
        __syncthreads();

        // O += P @ V
        for (int k4 = 0; k4 < 64; k4 += 4) {
            float pk[4][4];
            #pragma unroll
            for (int i = 0; i < 4; ++i)
                *(float4*)&pk[i][0] = *(const float4*)&KtPs[ty * 4 + i][k4];
            #pragma unroll
            for (int e = 0; e < 4; ++e) {
                float4 vv = *(const float4*)&Vs[k4 + e][tx * 4];
                #pragma unroll
                for (int i = 0; i < 4; ++i) {
                    acc[i][0] += pk[i][e] * vv.x;
                    acc[i][1] += pk[i][e] * vv.y;
                    acc[i][2] += pk[i][e] * vv.z;
                    acc[i][3] += pk[i][e] * vv.w;
                }
            }
        }
    }

    #pragma unroll
    for (int i = 0; i < 4; ++i) {
        int qr = q0 + ty * 4 + i;
        if (qr >= NTOK) break;
        float inv = 1.0f / l_run[i];
        float4 o = make_float4(acc[i][0] * inv, acc[i][1] * inv,
                               acc[i][2] * inv, acc[i][3] * inv);
        *(float4*)(O + base + (size_t)qr * DMODEL + tx * 4) = o;
    }
}

// ---------------- classifier head ----------------
__global__ void head_kernel(const float* __restrict__ clsl,
                            const float* __restrict__ hw,
                            const float* __restrict__ hb,
                            float* __restrict__ out)
{
    int i = blockIdx.x * 256 + threadIdx.x;
    if (i >= BATCH * NCLS) return;
    int b = i / NCLS, c = i % NCLS;
    const float* xr = clsl + b * DMODEL;
    float acc = hb[c];
    for (int t = 0; t < DMODEL; ++t) acc += xr[t] * hw[t * NCLS + c];
    out[i] = acc;
}

// ---------------- launch ----------------
extern "C" void kernel_launch(void* const* d_in, const int* in_sizes, int n_in,
                              void* d_out, int out_size, void* d_ws, size_t ws_size,
                              hipStream_t stream) {
    const float* x      = (const float*)d_in[0];
    const float* conv_w = (const float*)d_in[1];
    const float* conv_b = (const float*)d_in[2];
    const float* cls_tok= (const float*)d_in[3];
    const float* ln1_g  = (const float*)d_in[4];
    const float* ln1_b  = (const float*)d_in[5];
    const float* wq     = (const float*)d_in[6];
    const float* bq     = (const float*)d_in[7];
    const float* wk     = (const float*)d_in[8];
    const float* bk     = (const float*)d_in[9];
    const float* wv     = (const float*)d_in[10];
    const float* bv     = (const float*)d_in[11];
    const float* wo     = (const float*)d_in[12];
    const float* bo     = (const float*)d_in[13];
    const float* ln2_g  = (const float*)d_in[14];
    const float* ln2_b  = (const float*)d_in[15];
    const float* w1     = (const float*)d_in[16];
    const float* b1     = (const float*)d_in[17];
    const float* w2     = (const float*)d_in[18];
    const float* b2     = (const float*)d_in[19];
    const float* lnf_g  = (const float*)d_in[20];
    const float* lnf_b  = (const float*)d_in[21];
    const float* head_w = (const float*)d_in[22];
    const float* head_b = (const float*)d_in[23];

    float* ws = (float*)d_ws;
    const size_t TOKSZ = (size_t)NROWS * DMODEL;
    float* h    = ws;
    float* y    = h + TOKSZ;      // also reused as ctx
    float* q    = y + TOKSZ;
    float* k    = q + TOKSZ;
    float* v    = k + TOKSZ;
    float* hid  = v + TOKSZ;      // NROWS * HIDDEN
    float* cosb = hid + (size_t)NROWS * HIDDEN;
    float* sinb = cosb + (size_t)NTOK * 128;
    float* clsl = sinb + (size_t)NTOK * 128;

    rope_tab_kernel<<<(NTOK * 128 + 255) / 256, 256, 0, stream>>>(cosb, sinb);
    cls_kernel<<<BATCH, 256, 0, stream>>>(cls_tok, h);
    patch_embed_kernel<<<BATCH * 128, 256, 0, stream>>>(x, conv_w, conv_b, h);

    const int M = NROWS;
    dim3 g256(DMODEL / 64, (M + 63) / 64);
    dim3 g1024(HIDDEN / 64, (M + 63) / 64);
    int lnGrid = (M + 3) / 4;
    dim3 agrid(17, BATCH * NHEADS);

    for (int l = 0; l < LAYERS; ++l) {
        const float* Wq = wq + (size_t)l * DMODEL * DMODEL;
        const float* Wk = wk + (size_t)l * DMODEL * DMODEL;
        const float* Wv = wv + (size_t)l * DMODEL * DMODEL;
        const float* Wo = wo + (size_t)l * DMODEL * DMODEL;
        const float* W1 = w1 + (size_t)l * DMODEL * HIDDEN;
        const float* W2 = w2 + (size_t)l * HIDDEN * DMODEL;

        ln_kernel<<<lnGrid, 256, 0, stream>>>(h, y, ln1_g + l * DMODEL, ln1_b + l * DMODEL,
                                              M, DMODEL, DMODEL);
        gemm_ep_kernel<EPI_ROPE><<<g256, 256, 0, stream>>>(
            y, Wq, bq + l * DMODEL, q, cosb, sinb, M, DMODEL, DMODEL);
        gemm_ep_kernel<EPI_ROPE><<<g256, 256, 0, stream>>>(
            y, Wk, bk + l * DMODEL, k, cosb, sinb, M, DMODEL, DMODEL);
        gemm_ep_kernel<EPI_BIAS><<<g256, 256, 0, stream>>>(
            y, Wv, bv + l * DMODEL, v, nullptr, nullptr, M, DMODEL, DMODEL);
        flash_attn_kernel<<<agrid, 256, 0, stream>>>(q, k, v, y);
        gemm_ep_kernel<EPI_RES><<<g256, 256, 0, stream>>>(
            y, Wo, bo + l * DMODEL, h, nullptr, nullptr, M, DMODEL, DMODEL);
        ln_kernel<<<lnGrid, 256, 0, stream>>>(h, y, ln2_g + l * DMODEL, ln2_b + l * DMODEL,
                                              M, DMODEL, DMODEL);
        gemm_ep_kernel<EPI_GELU><<<g1024, 256, 0, stream>>>(
            y, W1, b1 + l * HIDDEN, hid, nullptr, nullptr, M, DMODEL, HIDDEN);
        gemm_ep_kernel<EPI_RES><<<g256, 256, 0, stream>>>(
            hid, W2, b2 + l * DMODEL, h, nullptr, nullptr, M, HIDDEN, DMODEL);
    }
    ln_kernel<<<(BATCH + 3) / 4, 256, 0, stream>>>(h, clsl, lnf_g, lnf_b,
                                                   BATCH, (long)NTOK * DMODEL, DMODEL);
    head_kernel<<<(BATCH * NCLS + 255) / 256, 256, 0, stream>>>(clsl, head_w, head_b,
                                                                (float*)d_out);
}

// Round 3
// 1952.338 us; speedup vs baseline: 18.1436x; 3.1510x over previous
//
#include <hip/hip_runtime.h>
#include <hip/hip_bf16.h>
#include <math.h>

// ---------------- constants ----------------
#define BATCH 16
#define CIN 3
#define SIMG 512
#define PPATCH 16
#define DMODEL 256
#define HIDDEN 1024
#define LAYERS 8
#define NHEADS 4
#define DHEAD 64
#define NTOK 1025            // 1024 patches + cls
#define NROWS (BATCH * NTOK) // 16400
#define NCLS 1000
#define VSTR 1032            // padded token stride for vT (16B-aligned rows)

typedef __attribute__((ext_vector_type(8))) short bf16x8;
typedef __attribute__((ext_vector_type(4))) float f32x4;

#define MFMA16(a, b, c) __builtin_amdgcn_mfma_f32_16x16x32_bf16(a, b, c, 0, 0, 0)

__device__ __forceinline__ ushort f2bf(float f) {
    union { float f; unsigned u; } v; v.f = f;
    unsigned r = v.u + 0x7fff + ((v.u >> 16) & 1);
    return (ushort)(r >> 16);
}
// byte offset into a [rows][64]-bf16 LDS tile (128B rows), XOR-swizzled
__device__ __forceinline__ int swz16(int row, int bcol) {
    return row * 128 + (bcol ^ ((row & 7) << 4));
}

// ---------------- RoPE tables ----------------
__global__ void rope_tab_kernel(float* __restrict__ cosb, float* __restrict__ sinb) {
    int i = blockIdx.x * 256 + threadIdx.x;
    if (i >= NTOK * 128) return;
    int n = i >> 7, j = i & 127;
    float inv = powf(10000.0f, -(float)(2 * j) / 256.0f);
    float ang = (float)n * inv;
    cosb[i] = cosf(ang);
    sinb[i] = sinf(ang);
}

// ---------------- cls token broadcast ----------------
__global__ void cls_kernel(const float* __restrict__ cls, float* __restrict__ tok) {
    int i = blockIdx.x * 256 + threadIdx.x;
    int b = i >> 8, d = i & 255;
    tok[(size_t)b * NTOK * DMODEL + d] = cls[d];
}

// ---------------- weight transpose + bf16 convert: WT[n][k] = bf16(W[k][n]) ----------------
__global__ __launch_bounds__(256) void transpose_cvt_kernel(
    const float* __restrict__ W, ushort* __restrict__ WT, int K, int N)
{
    __shared__ float t[32][33];
    int l = blockIdx.z;
    W  += (size_t)l * K * N;
    WT += (size_t)l * K * N;
    int kb = blockIdx.y * 32, nb = blockIdx.x * 32;
    int tx = threadIdx.x & 31, ty = threadIdx.x >> 5;
    #pragma unroll
    for (int i = 0; i < 32; i += 8)
        t[ty + i][tx] = W[(size_t)(kb + ty + i) * N + nb + tx];
    __syncthreads();
    #pragma unroll
    for (int i = 0; i < 32; i += 8)
        WT[(size_t)(nb + ty + i) * K + kb + tx] = f2bf(t[tx][ty + i]);
}

// ---------------- patch embed (fp32, writes residual h) ----------------
#define NPB 8
__global__ __launch_bounds__(256) void patch_embed_kernel(
    const float* __restrict__ x, const float* __restrict__ w,
    const float* __restrict__ cb, float* __restrict__ tok)
{
    __shared__ __align__(16) float xs[CIN * PPATCH * NPB * PPATCH];
    int blk = blockIdx.x;
    int b = blk >> 7;
    int pg = blk & 127;
    int ph = pg >> 2;
    int pw0 = (pg & 3) * NPB;
    int tid = threadIdx.x;
    for (int i4 = tid; i4 < 1536; i4 += 256) {
        int i = i4 * 4;
        int q = i & 15, u = (i >> 4) & 7, p = (i >> 7) & 15, c = i >> 11;
        const float* src = x + (((size_t)(b * CIN + c) * SIMG) + ph * PPATCH + p) * SIMG
                             + (pw0 + u) * PPATCH + q;
        *(float4*)&xs[i] = *(const float4*)src;
    }
    __syncthreads();
    int d = tid;
    const float* wr = w + (size_t)d * 768;
    float acc[NPB] = {};
    for (int cp = 0; cp < 48; ++cp) {
        #pragma unroll
        for (int q4 = 0; q4 < 4; ++q4) {
            float4 wv = *(const float4*)(wr + cp * 16 + q4 * 4);
            #pragma unroll
            for (int u = 0; u < NPB; ++u) {
                float4 xv = *(const float4*)&xs[(cp * 8 + u) * 16 + q4 * 4];
                acc[u] += wv.x * xv.x + wv.y * xv.y + wv.z * xv.z + wv.w * xv.w;
            }
        }
    }
    float bd = cb[d];
    for (int u = 0; u < NPB; ++u) {
        int pi = ph * 32 + pw0 + u;
        tok[((size_t)b * NTOK + 1 + pi) * DMODEL + d] = acc[u] + bd;
    }
}

// ---------------- layernorm: one wave per 256-wide row ----------------
template <bool BF>
__global__ __launch_bounds__(256) void ln_kernel(
    const float* __restrict__ in, void* __restrict__ outp,
    const float* __restrict__ g, const float* __restrict__ bta,
    int nrows, long in_stride, long out_stride)
{
    int row = blockIdx.x * 4 + (threadIdx.x >> 6);
    int lane = threadIdx.x & 63;
    if (row >= nrows) return;
    const float* xr = in + (size_t)row * in_stride;
    float4 v = *(const float4*)(xr + lane * 4);
    float s = v.x + v.y + v.z + v.w;
    float ss = v.x * v.x + v.y * v.y + v.z * v.z + v.w * v.w;
    #pragma unroll
    for (int m = 1; m < 64; m <<= 1) {
        s += __shfl_xor(s, m, 64);
        ss += __shfl_xor(ss, m, 64);
    }
    float mean = s * (1.0f / 256.0f);
    float var = ss * (1.0f / 256.0f) - mean * mean;
    float inv = rsqrtf(var + 1e-5f);
    float4 gv = *(const float4*)(g + lane * 4);
    float4 bv = *(const float4*)(bta + lane * 4);
    float o0 = (v.x - mean) * inv * gv.x + bv.x;
    float o1 = (v.y - mean) * inv * gv.y + bv.y;
    float o2 = (v.z - mean) * inv * gv.z + bv.z;
    float o3 = (v.w - mean) * inv * gv.w + bv.w;
    if (BF) {
        ushort4 o = make_ushort4(f2bf(o0), f2bf(o1), f2bf(o2), f2bf(o3));
        *(ushort4*)((ushort*)outp + (size_t)row * out_stride + lane * 4) = o;
    } else {
        *(float4*)((float*)outp + (size_t)row * out_stride + lane * 4) =
            make_float4(o0, o1, o2, o3);
    }
}

// ---------------- MFMA bf16 GEMM: C[M,Nf] = A[M,K] @ WT[Nf,K]^T ----------------
// EPI: 0 = bias+RoPE -> bf16, 1 = bias -> bf16 transposed vT[d][tok],
//      2 = bias+residual-add -> fp32 Cf, 3 = bias+GELU -> bf16
template <int EPI>
__global__ __launch_bounds__(256) void gemm_mfma(
    const ushort* __restrict__ A, const ushort* __restrict__ WT,
    const float* __restrict__ bias, float* __restrict__ Cf, ushort* __restrict__ Cbf,
    const float* __restrict__ cosb, const float* __restrict__ sinb,
    int M, int K, int Nf)
{
    __shared__ __align__(16) ushort As[128 * 64];
    __shared__ __align__(16) ushort Bs[64 * 64];
    int tid = threadIdx.x;
    int w = tid >> 6, l = tid & 63;
    int lr = l & 15, lg = l >> 4;
    int wm = w & 1, wn = w >> 1;
    int m0 = blockIdx.y * 128;
    int n0 = blockIdx.x * 64;

    f32x4 acc[4][2] = {};

    for (int k0 = 0; k0 < K; k0 += 64) {
        __syncthreads();
        #pragma unroll
        for (int i = 0; i < 4; ++i) {
            int id = tid + 256 * i; int r = id >> 3, c8 = id & 7;
            int mrow = m0 + r; if (mrow > M - 1) mrow = M - 1;
            uint4 t = *(const uint4*)(A + (size_t)mrow * K + k0 + c8 * 8);
            *(uint4*)((char*)As + swz16(r, c8 * 16)) = t;
        }
        #pragma unroll
        for (int i = 0; i < 2; ++i) {
            int id = tid + 256 * i; int r = id >> 3, c8 = id & 7;
            uint4 t = *(const uint4*)(WT + (size_t)(n0 + r) * K + k0 + c8 * 8);
            *(uint4*)((char*)Bs + swz16(r, c8 * 16)) = t;
        }
        __syncthreads();
        #pragma unroll
        for (int ks = 0; ks < 2; ++ks) {
            bf16x8 af[4];
            #pragma unroll
            for (int mf = 0; mf < 4; ++mf)
                af[mf] = *(const bf16x8*)((char*)As + swz16(wm * 64 + mf * 16 + lr, ks * 64 + lg * 16));
            #pragma unroll
            for (int nf = 0; nf < 2; ++nf) {
                bf16x8 bfr = *(const bf16x8*)((char*)Bs + swz16(wn * 32 + nf * 16 + lr, ks * 64 + lg * 16));
                #pragma unroll
                for (int mf = 0; mf < 4; ++mf)
                    acc[mf][nf] = MFMA16(af[mf], bfr, acc[mf][nf]);
            }
        }
    }

    #pragma unroll
    for (int mf = 0; mf < 4; ++mf) {
        #pragma unroll
        for (int nf = 0; nf < 2; ++nf) {
            int n = n0 + wn * 32 + nf * 16 + lr;
            float bb = bias[n];
            #pragma unroll
            for (int e = 0; e < 4; ++e) {
                int m = m0 + wm * 64 + mf * 16 + lg * 4 + e;
                float v = acc[mf][nf][e] + bb;
                if (EPI == 0) {
                    float pv = __shfl_xor(v, 1, 64);  // partner column n^1 (uniform pairs)
                    int tok = m % NTOK;
                    int j = n >> 1;
                    float c = cosb[tok * 128 + j], s = sinb[tok * 128 + j];
                    float o = (n & 1) ? (pv * s + v * c) : (v * c - pv * s);
                    if (m < M) Cbf[(size_t)m * Nf + n] = f2bf(o);
                } else if (EPI == 1) {
                    if (m < M) {
                        int b_ = m / NTOK, tok = m - b_ * NTOK;
                        Cbf[((size_t)(b_ * 256 + n)) * VSTR + tok] = f2bf(v);
                    }
                } else if (EPI == 2) {
                    if (m < M) Cf[(size_t)m * Nf + n] += v;
                } else {
                    if (m < M) {
                        float gg = 0.5f * v * (1.0f + erff(v * 0.70710678118f));
                        Cbf[(size_t)m * Nf + n] = f2bf(gg);
                    }
                }
            }
        }
    }
}

// ---------------- flash attention, MFMA bf16 ----------------
// grid (17 q-tiles, 64 b*h); block 256 = 4 waves; wave w owns q-rows [w*16, w*16+16)
__global__ __launch_bounds__(256) void flash_mfma(
    const ushort* __restrict__ Qb, const ushort* __restrict__ Kb,
    const ushort* __restrict__ Vt, ushort* __restrict__ Ctx)
{
    __shared__ __align__(16) ushort Qs[64 * 64];
    __shared__ __align__(16) ushort Ks[64 * 64];
    __shared__ __align__(16) ushort Vs[64 * 64];
    __shared__ __align__(16) ushort Ps[64 * 64];

    int tid = threadIdx.x;
    int w = tid >> 6, l = tid & 63;
    int lr = l & 15, lg = l >> 4;
    int bh = blockIdx.y;
    int b = bh >> 2, h = bh & 3;
    int q0 = blockIdx.x * 64;
    const size_t rowbase = (size_t)b * NTOK;
    const size_t vbase = (size_t)(b * 256 + h * 64) * VSTR;

    // stage Q tile once (visibility covered by first in-loop barrier)
    #pragma unroll
    for (int i = 0; i < 2; ++i) {
        int id = tid + 256 * i; int r = id >> 3, c8 = id & 7;
        int qr = q0 + r; if (qr > 1024) qr = 1024;
        uint4 t = *(const uint4*)(Qb + (rowbase + qr) * 256 + h * 64 + c8 * 8);
        *(uint4*)((char*)Qs + swz16(r, c8 * 16)) = t;
    }

    f32x4 po[4] = {};
    float m_run[4] = {-1e30f, -1e30f, -1e30f, -1e30f};
    float l_run[4] = {0.f, 0.f, 0.f, 0.f};

    for (int kt = 0; kt < 17; ++kt) {
        __syncthreads();  // prior-iter LDS reads done
        #pragma unroll
        for (int i = 0; i < 2; ++i) {
            int id = tid + 256 * i; int r = id >> 3, c8 = id & 7;
            int kr = kt * 64 + r; int kcl = kr > 1024 ? 1024 : kr;
            uint4 tk = *(const uint4*)(Kb + (rowbase + kcl) * 256 + h * 64 + c8 * 8);
            *(uint4*)((char*)Ks + swz16(r, c8 * 16)) = tk;
            uint4 tv = *(const uint4*)(Vt + vbase + (size_t)r * VSTR + kt * 64 + c8 * 8);
            *(uint4*)((char*)Vs + swz16(r, c8 * 16)) = tv;
        }
        __syncthreads();

        // S = Q @ K^T  (A: Qs rows = q, B: Ks rows = k-col)
        f32x4 sa[4] = {};
        #pragma unroll
        for (int ks = 0; ks < 2; ++ks) {
            bf16x8 qa = *(const bf16x8*)((char*)Qs + swz16(w * 16 + lr, ks * 64 + lg * 16));
            #pragma unroll
            for (int nf = 0; nf < 4; ++nf) {
                bf16x8 kb = *(const bf16x8*)((char*)Ks + swz16(nf * 16 + lr, ks * 64 + lg * 16));
                sa[nf] = MFMA16(qa, kb, sa[nf]);
            }
        }

        // scale + mask
        #pragma unroll
        for (int nf = 0; nf < 4; ++nf) {
            int kc = kt * 64 + nf * 16 + lr;
            bool msk = kc > 1024;
            #pragma unroll
            for (int e = 0; e < 4; ++e)
                sa[nf][e] = msk ? -1e30f : sa[nf][e] * 0.125f;
        }
        // online softmax per row (rows live across 16-lane groups)
        #pragma unroll
        for (int e = 0; e < 4; ++e) {
            float mx = fmaxf(fmaxf(sa[0][e], sa[1][e]), fmaxf(sa[2][e], sa[3][e]));
            #pragma unroll
            for (int t = 1; t < 16; t <<= 1) mx = fmaxf(mx, __shfl_xor(mx, t, 16));
            float mnew = fmaxf(m_run[e], mx);
            float sc = __expf(m_run[e] - mnew);
            float rs = 0.f;
            #pragma unroll
            for (int nf = 0; nf < 4; ++nf) {
                float p = __expf(sa[nf][e] - mnew);
                sa[nf][e] = p;
                rs += p;
            }
            #pragma unroll
            for (int t = 1; t < 16; t <<= 1) rs += __shfl_xor(rs, t, 16);
            l_run[e] = l_run[e] * sc + rs;
            m_run[e] = mnew;
            #pragma unroll
            for (int d = 0; d < 4; ++d) po[d][e] *= sc;
        }
        // P -> bf16 into wave-private LDS rows
        #pragma unroll
        for (int nf = 0; nf < 4; ++nf) {
            #pragma unroll
            for (int e = 0; e < 4; ++e) {
                int pr = w * 16 + lg * 4 + e;
                int pc = nf * 16 + lr;
                *(ushort*)((char*)Ps + swz16(pr, pc * 2)) = f2bf(sa[nf][e]);
            }
        }
        __syncthreads();

        // O += P @ V   (A: Ps rows = q, B: Vs rows = d)
        #pragma unroll
        for (int ks = 0; ks < 2; ++ks) {
            bf16x8 pa = *(const bf16x8*)((char*)Ps + swz16(w * 16 + lr, ks * 64 + lg * 16));
            #pragma unroll
            for (int d = 0; d < 4; ++d) {
                bf16x8 vb = *(const bf16x8*)((char*)Vs + swz16(d * 16 + lr, ks * 64 + lg * 16));
                po[d] = MFMA16(pa, vb, po[d]);
            }
        }
    }

    #pragma unroll
    for (int e = 0; e < 4; ++e) {
        int qr = q0 + w * 16 + lg * 4 + e;
        if (qr <= 1024) {
            float inv = 1.0f / l_run[e];
            #pragma unroll
            for (int d = 0; d < 4; ++d)
                Ctx[(rowbase + qr) * 256 + h * 64 + d * 16 + lr] = f2bf(po[d][e] * inv);
        }
    }
}

// ---------------- classifier head ----------------
__global__ void head_kernel(const float* __restrict__ clsl,
                            const float* __restrict__ hw,
                            const float* __restrict__ hb,
                            float* __restrict__ out)
{
    int i = blockIdx.x * 256 + threadIdx.x;
    if (i >= BATCH * NCLS) return;
    int b = i / NCLS, c = i % NCLS;
    const float* xr = clsl + b * DMODEL;
    float acc = hb[c];
    for (int t = 0; t < DMODEL; ++t) acc += xr[t] * hw[t * NCLS + c];
    out[i] = acc;
}

// ---------------- launch ----------------
extern "C" void kernel_launch(void* const* d_in, const int* in_sizes, int n_in,
                              void* d_out, int out_size, void* d_ws, size_t ws_size,
                              hipStream_t stream) {
    const float* x      = (const float*)d_in[0];
    const float* conv_w = (const float*)d_in[1];
    const float* conv_b = (const float*)d_in[2];
    const float* cls_tok= (const float*)d_in[3];
    const float* ln1_g  = (const float*)d_in[4];
    const float* ln1_b  = (const float*)d_in[5];
    const float* wq     = (const float*)d_in[6];
    const float* bq     = (const float*)d_in[7];
    const float* wk     = (const float*)d_in[8];
    const float* bk     = (const float*)d_in[9];
    const float* wv     = (const float*)d_in[10];
    const float* bv     = (const float*)d_in[11];
    const float* wo     = (const float*)d_in[12];
    const float* bo     = (const float*)d_in[13];
    const float* ln2_g  = (const float*)d_in[14];
    const float* ln2_b  = (const float*)d_in[15];
    const float* w1     = (const float*)d_in[16];
    const float* b1     = (const float*)d_in[17];
    const float* w2     = (const float*)d_in[18];
    const float* b2     = (const float*)d_in[19];
    const float* lnf_g  = (const float*)d_in[20];
    const float* lnf_b  = (const float*)d_in[21];
    const float* head_w = (const float*)d_in[22];
    const float* head_b = (const float*)d_in[23];

    char* p = (char*)d_ws;
    float* h    = (float*)p;            p += (size_t)NROWS * DMODEL * 4;
    float* cosb = (float*)p;            p += (size_t)NTOK * 128 * 4;
    float* sinb = (float*)p;            p += (size_t)NTOK * 128 * 4;
    float* clsl = (float*)p;            p += (size_t)BATCH * DMODEL * 4;
    ushort* ybf = (ushort*)p;           p += (size_t)NROWS * DMODEL * 2;
    ushort* qbf = (ushort*)p;           p += (size_t)NROWS * DMODEL * 2;
    ushort* kbf = (ushort*)p;           p += (size_t)NROWS * DMODEL * 2;
    ushort* vT  = (ushort*)p;           p += (size_t)BATCH * 256 * VSTR * 2 + 256;
    ushort* hidbf = (ushort*)p;         p += (size_t)NROWS * HIDDEN * 2;
    ushort* wqT = (ushort*)p;           p += (size_t)LAYERS * DMODEL * DMODEL * 2;
    ushort* wkT = (ushort*)p;           p += (size_t)LAYERS * DMODEL * DMODEL * 2;
    ushort* wvT = (ushort*)p;           p += (size_t)LAYERS * DMODEL * DMODEL * 2;
    ushort* woT = (ushort*)p;           p += (size_t)LAYERS * DMODEL * DMODEL * 2;
    ushort* w1T = (ushort*)p;           p += (size_t)LAYERS * DMODEL * HIDDEN * 2;
    ushort* w2T = (ushort*)p;           p += (size_t)LAYERS * DMODEL * HIDDEN * 2;

    // one-time prep (deterministic, every call)
    transpose_cvt_kernel<<<dim3(8, 8, LAYERS), 256, 0, stream>>>(wq, wqT, 256, 256);
    transpose_cvt_kernel<<<dim3(8, 8, LAYERS), 256, 0, stream>>>(wk, wkT, 256, 256);
    transpose_cvt_kernel<<<dim3(8, 8, LAYERS), 256, 0, stream>>>(wv, wvT, 256, 256);
    transpose_cvt_kernel<<<dim3(8, 8, LAYERS), 256, 0, stream>>>(wo, woT, 256, 256);
    transpose_cvt_kernel<<<dim3(32, 8, LAYERS), 256, 0, stream>>>(w1, w1T, 256, 1024);
    transpose_cvt_kernel<<<dim3(8, 32, LAYERS), 256, 0, stream>>>(w2, w2T, 1024, 256);
    rope_tab_kernel<<<(NTOK * 128 + 255) / 256, 256, 0, stream>>>(cosb, sinb);
    cls_kernel<<<BATCH, 256, 0, stream>>>(cls_tok, h);
    patch_embed_kernel<<<BATCH * 128, 256, 0, stream>>>(x, conv_w, conv_b, h);

    const int M = NROWS;
    dim3 g256(4, 129), g1024(16, 129);
    int lnGrid = (M + 3) / 4;
    dim3 agrid(17, BATCH * NHEADS);

    for (int l = 0; l < LAYERS; ++l) {
        const ushort* WqT = wqT + (size_t)l * DMODEL * DMODEL;
        const ushort* WkT = wkT + (size_t)l * DMODEL * DMODEL;
        const ushort* WvT = wvT + (size_t)l * DMODEL * DMODEL;
        const ushort* WoT = woT + (size_t)l * DMODEL * DMODEL;
        const ushort* W1T = w1T + (size_t)l * DMODEL * HIDDEN;
        const ushort* W2T = w2T + (size_t)l * DMODEL * HIDDEN;

        ln_kernel<true><<<lnGrid, 256, 0, stream>>>(h, ybf, ln1_g + l * DMODEL,
                                                    ln1_b + l * DMODEL, M, DMODEL, DMODEL);
        gemm_mfma<0><<<g256, 256, 0, stream>>>(ybf, WqT, bq + l * DMODEL, nullptr, qbf,
                                               cosb, sinb, M, DMODEL, DMODEL);
        gemm_mfma<0><<<g256, 256, 0, stream>>>(ybf, WkT, bk + l * DMODEL, nullptr, kbf,
                                               cosb, sinb, M, DMODEL, DMODEL);
        gemm_mfma<1><<<g256, 256, 0, stream>>>(ybf, WvT, bv + l * DMODEL, nullptr, vT,
                                               nullptr, nullptr, M, DMODEL, DMODEL);
        flash_mfma<<<agrid, 256, 0, stream>>>(qbf, kbf, vT, ybf);
        gemm_mfma<2><<<g256, 256, 0, stream>>>(ybf, WoT, bo + l * DMODEL, h, nullptr,
                                               nullptr, nullptr, M, DMODEL, DMODEL);
        ln_kernel<true><<<lnGrid, 256, 0, stream>>>(h, ybf, ln2_g + l * DMODEL,
                                                    ln2_b + l * DMODEL, M, DMODEL, DMODEL);
        gemm_mfma<3><<<g1024, 256, 0, stream>>>(ybf, W1T, b1 + l * HIDDEN, nullptr, hidbf,
                                                nullptr, nullptr, M, DMODEL, HIDDEN);
        gemm_mfma<2><<<g256, 256, 0, stream>>>(hidbf, W2T, b2 + l * DMODEL, h, nullptr,
                                               nullptr, nullptr, M, HIDDEN, DMODEL);
    }
    ln_kernel<false><<<(BATCH + 3) / 4, 256, 0, stream>>>(h, clsl, lnf_g, lnf_b,
                                                          BATCH, (long)NTOK * DMODEL, DMODEL);
    head_kernel<<<(BATCH * NCLS + 255) / 256, 256, 0, stream>>>(clsl, head_w, head_b,
                                                                (float*)d_out);
}

// Round 4
// 1708.789 us; speedup vs baseline: 20.7295x; 1.1425x over previous
//
#include <hip/hip_runtime.h>
#include <hip/hip_bf16.h>
#include <math.h>

// ---------------- constants ----------------
#define BATCH 16
#define CIN 3
#define SIMG 512
#define PPATCH 16
#define DMODEL 256
#define HIDDEN 1024
#define LAYERS 8
#define NHEADS 4
#define DHEAD 64
#define NTOK 1025            // 1024 patches + cls
#define NROWS (BATCH * NTOK) // 16400
#define NCLS 1000
#define VSTR 1032            // padded token stride for vT (16B-aligned rows)

typedef __attribute__((ext_vector_type(8))) short bf16x8;
typedef __attribute__((ext_vector_type(4))) float f32x4;

#define MFMA16(a, b, c) __builtin_amdgcn_mfma_f32_16x16x32_bf16(a, b, c, 0, 0, 0)

__device__ __forceinline__ ushort f2bf(float f) {
    union { float f; unsigned u; } v; v.f = f;
    unsigned r = v.u + 0x7fff + ((v.u >> 16) & 1);
    return (ushort)(r >> 16);
}
__device__ __forceinline__ unsigned pk2(ushort a, ushort b) {
    return (unsigned)a | ((unsigned)b << 16);
}
// byte offset into a [rows][64]-bf16 LDS tile (128B rows), XOR-swizzled
__device__ __forceinline__ int swz16(int row, int bcol) {
    return row * 128 + (bcol ^ ((row & 7) << 4));
}

// ---------------- RoPE tables ----------------
__global__ void rope_tab_kernel(float* __restrict__ cosb, float* __restrict__ sinb) {
    int i = blockIdx.x * 256 + threadIdx.x;
    if (i >= NTOK * 128) return;
    int n = i >> 7, j = i & 127;
    float inv = powf(10000.0f, -(float)(2 * j) / 256.0f);
    float ang = (float)n * inv;
    cosb[i] = cosf(ang);
    sinb[i] = sinf(ang);
}

// ---------------- cls token broadcast ----------------
__global__ void cls_kernel(const float* __restrict__ cls, float* __restrict__ tok) {
    int i = blockIdx.x * 256 + threadIdx.x;
    int b = i >> 8, d = i & 255;
    tok[(size_t)b * NTOK * DMODEL + d] = cls[d];
}

// ---------------- bf16 convert (conv weight, already [N][K]) ----------------
__global__ void cvt_bf16_kernel(const float* __restrict__ in, ushort* __restrict__ out, int n) {
    int base = (blockIdx.x * 256 + threadIdx.x) * 4;
    if (base >= n) return;
    float4 v = *(const float4*)(in + base);
    *(ushort4*)(out + base) = make_ushort4(f2bf(v.x), f2bf(v.y), f2bf(v.z), f2bf(v.w));
}

// ---------------- weight transpose + bf16 convert: WT[n][k] = bf16(W[k][n]) ----------------
__global__ __launch_bounds__(256) void transpose_cvt_kernel(
    const float* __restrict__ W, ushort* __restrict__ WT, int K, int N,
    long wl, long wtl)
{
    __shared__ float t[32][33];
    int l = blockIdx.z;
    W  += (size_t)l * wl;
    WT += (size_t)l * wtl;
    int kb = blockIdx.y * 32, nb = blockIdx.x * 32;
    int tx = threadIdx.x & 31, ty = threadIdx.x >> 5;
    #pragma unroll
    for (int i = 0; i < 32; i += 8)
        t[ty + i][tx] = W[(size_t)(kb + ty + i) * N + nb + tx];
    __syncthreads();
    #pragma unroll
    for (int i = 0; i < 32; i += 8)
        WT[(size_t)(nb + ty + i) * K + kb + tx] = f2bf(t[tx][ty + i]);
}

// ---------------- layernorm: one wave per 256-wide row ----------------
template <bool BF>
__global__ __launch_bounds__(256) void ln_kernel(
    const float* __restrict__ in, void* __restrict__ outp,
    const float* __restrict__ g, const float* __restrict__ bta,
    int nrows, long in_stride, long out_stride)
{
    int row = blockIdx.x * 4 + (threadIdx.x >> 6);
    int lane = threadIdx.x & 63;
    if (row >= nrows) return;
    const float* xr = in + (size_t)row * in_stride;
    float4 v = *(const float4*)(xr + lane * 4);
    float s = v.x + v.y + v.z + v.w;
    float ss = v.x * v.x + v.y * v.y + v.z * v.z + v.w * v.w;
    #pragma unroll
    for (int m = 1; m < 64; m <<= 1) {
        s += __shfl_xor(s, m, 64);
        ss += __shfl_xor(ss, m, 64);
    }
    float mean = s * (1.0f / 256.0f);
    float var = ss * (1.0f / 256.0f) - mean * mean;
    float inv = rsqrtf(var + 1e-5f);
    float4 gv = *(const float4*)(g + lane * 4);
    float4 bv = *(const float4*)(bta + lane * 4);
    float o0 = (v.x - mean) * inv * gv.x + bv.x;
    float o1 = (v.y - mean) * inv * gv.y + bv.y;
    float o2 = (v.z - mean) * inv * gv.z + bv.z;
    float o3 = (v.w - mean) * inv * gv.w + bv.w;
    if (BF) {
        ushort4 o = make_ushort4(f2bf(o0), f2bf(o1), f2bf(o2), f2bf(o3));
        *(ushort4*)((ushort*)outp + (size_t)row * out_stride + lane * 4) = o;
    } else {
        *(float4*)((float*)outp + (size_t)row * out_stride + lane * 4) =
            make_float4(o0, o1, o2, o3);
    }
}

// ---------------- patch embed as MFMA GEMM (fused im2col) ----------------
__global__ __launch_bounds__(256) void patch_gemm(
    const float* __restrict__ x, const ushort* __restrict__ Wb,
    const float* __restrict__ bias, float* __restrict__ h)
{
    __shared__ __align__(16) ushort As[128 * 64];
    __shared__ __align__(16) ushort Bs[64 * 64];
    int tid = threadIdx.x;
    int w = tid >> 6, l = tid & 63;
    int lr = l & 15, lg = l >> 4;
    int wm = w & 1, wn = w >> 1;
    int m0 = blockIdx.y * 128;
    int n0 = blockIdx.x * 64;
    f32x4 acc[4][2] = {};

    for (int k0 = 0; k0 < 768; k0 += 64) {
        __syncthreads();
        #pragma unroll
        for (int i = 0; i < 4; ++i) {
            int id = tid + 256 * i; int r = id >> 3, c8 = id & 7;
            int m = m0 + r;
            int b_ = m >> 10, pi = m & 1023, ph = pi >> 5, pw = pi & 31;
            int k = k0 + c8 * 8;
            int c = k >> 8, rem = k & 255, pr = rem >> 4, q = rem & 15;
            const float* src = x + ((size_t)((b_ * 3 + c) * SIMG) + ph * 16 + pr) * SIMG
                                 + pw * 16 + q;
            float4 v0 = *(const float4*)src;
            float4 v1 = *(const float4*)(src + 4);
            uint4 t;
            t.x = pk2(f2bf(v0.x), f2bf(v0.y));
            t.y = pk2(f2bf(v0.z), f2bf(v0.w));
            t.z = pk2(f2bf(v1.x), f2bf(v1.y));
            t.w = pk2(f2bf(v1.z), f2bf(v1.w));
            *(uint4*)((char*)As + swz16(r, c8 * 16)) = t;
        }
        #pragma unroll
        for (int i = 0; i < 2; ++i) {
            int id = tid + 256 * i; int r = id >> 3, c8 = id & 7;
            uint4 t = *(const uint4*)(Wb + (size_t)(n0 + r) * 768 + k0 + c8 * 8);
            *(uint4*)((char*)Bs + swz16(r, c8 * 16)) = t;
        }
        __syncthreads();
        #pragma unroll
        for (int ks = 0; ks < 2; ++ks) {
            bf16x8 af[4];
            #pragma unroll
            for (int mf = 0; mf < 4; ++mf)
                af[mf] = *(const bf16x8*)((char*)As + swz16(wm * 64 + mf * 16 + lr, ks * 64 + lg * 16));
            #pragma unroll
            for (int nf = 0; nf < 2; ++nf) {
                bf16x8 bfr = *(const bf16x8*)((char*)Bs + swz16(wn * 32 + nf * 16 + lr, ks * 64 + lg * 16));
                #pragma unroll
                for (int mf = 0; mf < 4; ++mf)
                    acc[mf][nf] = MFMA16(af[mf], bfr, acc[mf][nf]);
            }
        }
    }
    #pragma unroll
    for (int mf = 0; mf < 4; ++mf) {
        #pragma unroll
        for (int nf = 0; nf < 2; ++nf) {
            int n = n0 + wn * 32 + nf * 16 + lr;
            float bb = bias[n];
            #pragma unroll
            for (int e = 0; e < 4; ++e) {
                int m = m0 + wm * 64 + mf * 16 + lg * 4 + e;
                int b_ = m >> 10, pi = m & 1023;
                h[((size_t)(b_ * NTOK + 1 + pi)) * DMODEL + n] = acc[mf][nf][e] + bb;
            }
        }
    }
}

// ---------------- fused QKV MFMA GEMM ----------------
__global__ __launch_bounds__(256) void gemm_qkv(
    const ushort* __restrict__ A, const ushort* __restrict__ WT,
    const float* __restrict__ bq, const float* __restrict__ bk,
    const float* __restrict__ bv,
    ushort* __restrict__ qbf, ushort* __restrict__ kbf, ushort* __restrict__ vT,
    const float* __restrict__ cosb, const float* __restrict__ sinb, int M)
{
    __shared__ __align__(16) ushort As[128 * 64];
    __shared__ __align__(16) ushort Bs[64 * 64];
    int tid = threadIdx.x;
    int w = tid >> 6, l = tid & 63;
    int lr = l & 15, lg = l >> 4;
    int wm = w & 1, wn = w >> 1;
    int m0 = blockIdx.y * 128;
    int n0 = blockIdx.x * 64;
    f32x4 acc[4][2] = {};

    for (int k0 = 0; k0 < 256; k0 += 64) {
        __syncthreads();
        #pragma unroll
        for (int i = 0; i < 4; ++i) {
            int id = tid + 256 * i; int r = id >> 3, c8 = id & 7;
            int mrow = m0 + r; if (mrow > M - 1) mrow = M - 1;
            uint4 t = *(const uint4*)(A + (size_t)mrow * 256 + k0 + c8 * 8);
            *(uint4*)((char*)As + swz16(r, c8 * 16)) = t;
        }
        #pragma unroll
        for (int i = 0; i < 2; ++i) {
            int id = tid + 256 * i; int r = id >> 3, c8 = id & 7;
            uint4 t = *(const uint4*)(WT + (size_t)(n0 + r) * 256 + k0 + c8 * 8);
            *(uint4*)((char*)Bs + swz16(r, c8 * 16)) = t;
        }
        __syncthreads();
        #pragma unroll
        for (int ks = 0; ks < 2; ++ks) {
            bf16x8 af[4];
            #pragma unroll
            for (int mf = 0; mf < 4; ++mf)
                af[mf] = *(const bf16x8*)((char*)As + swz16(wm * 64 + mf * 16 + lr, ks * 64 + lg * 16));
            #pragma unroll
            for (int nf = 0; nf < 2; ++nf) {
                bf16x8 bfr = *(const bf16x8*)((char*)Bs + swz16(wn * 32 + nf * 16 + lr, ks * 64 + lg * 16));
                #pragma unroll
                for (int mf = 0; mf < 4; ++mf)
                    acc[mf][nf] = MFMA16(af[mf], bfr, acc[mf][nf]);
            }
        }
    }

    #pragma unroll
    for (int mf = 0; mf < 4; ++mf) {
        #pragma unroll
        for (int nf = 0; nf < 2; ++nf) {
            int n = n0 + wn * 32 + nf * 16 + lr;   // 0..767, wave-uniform 256-range
            int sel = n >> 8, nc = n & 255;
            const float* bp = sel == 0 ? bq : (sel == 1 ? bk : bv);
            float bb = bp[nc];
            #pragma unroll
            for (int e = 0; e < 4; ++e) {
                int m = m0 + wm * 64 + mf * 16 + lg * 4 + e;
                float v = acc[mf][nf][e] + bb;
                if (sel < 2) {
                    float pv = __shfl_xor(v, 1, 64);   // partner column nc^1
                    int tok = m % NTOK;
                    int j = nc >> 1;
                    float c = cosb[tok * 128 + j], s = sinb[tok * 128 + j];
                    float o = (nc & 1) ? (pv * s + v * c) : (v * c - pv * s);
                    if (m < M) {
                        ushort* dst = sel == 0 ? qbf : kbf;
                        dst[(size_t)m * DMODEL + nc] = f2bf(o);
                    }
                } else if (m < M) {
                    int b_ = m / NTOK, tok = m - b_ * NTOK;
                    vT[((size_t)(b_ * 256 + nc)) * VSTR + tok] = f2bf(v);
                }
            }
        }
    }
}

// ---------------- generic MFMA GEMM: EPI 2 = bias+residual fp32, 3 = bias+GELU bf16 ----------------
template <int EPI>
__global__ __launch_bounds__(256) void gemm_mfma(
    const ushort* __restrict__ A, const ushort* __restrict__ WT,
    const float* __restrict__ bias, float* __restrict__ Cf, ushort* __restrict__ Cbf,
    int M, int K, int Nf)
{
    __shared__ __align__(16) ushort As[128 * 64];
    __shared__ __align__(16) ushort Bs[64 * 64];
    int tid = threadIdx.x;
    int w = tid >> 6, l = tid & 63;
    int lr = l & 15, lg = l >> 4;
    int wm = w & 1, wn = w >> 1;
    int m0 = blockIdx.y * 128;
    int n0 = blockIdx.x * 64;
    f32x4 acc[4][2] = {};

    for (int k0 = 0; k0 < K; k0 += 64) {
        __syncthreads();
        #pragma unroll
        for (int i = 0; i < 4; ++i) {
            int id = tid + 256 * i; int r = id >> 3, c8 = id & 7;
            int mrow = m0 + r; if (mrow > M - 1) mrow = M - 1;
            uint4 t = *(const uint4*)(A + (size_t)mrow * K + k0 + c8 * 8);
            *(uint4*)((char*)As + swz16(r, c8 * 16)) = t;
        }
        #pragma unroll
        for (int i = 0; i < 2; ++i) {
            int id = tid + 256 * i; int r = id >> 3, c8 = id & 7;
            uint4 t = *(const uint4*)(WT + (size_t)(n0 + r) * K + k0 + c8 * 8);
            *(uint4*)((char*)Bs + swz16(r, c8 * 16)) = t;
        }
        __syncthreads();
        #pragma unroll
        for (int ks = 0; ks < 2; ++ks) {
            bf16x8 af[4];
            #pragma unroll
            for (int mf = 0; mf < 4; ++mf)
                af[mf] = *(const bf16x8*)((char*)As + swz16(wm * 64 + mf * 16 + lr, ks * 64 + lg * 16));
            #pragma unroll
            for (int nf = 0; nf < 2; ++nf) {
                bf16x8 bfr = *(const bf16x8*)((char*)Bs + swz16(wn * 32 + nf * 16 + lr, ks * 64 + lg * 16));
                #pragma unroll
                for (int mf = 0; mf < 4; ++mf)
                    acc[mf][nf] = MFMA16(af[mf], bfr, acc[mf][nf]);
            }
        }
    }

    #pragma unroll
    for (int mf = 0; mf < 4; ++mf) {
        #pragma unroll
        for (int nf = 0; nf < 2; ++nf) {
            int n = n0 + wn * 32 + nf * 16 + lr;
            float bb = bias[n];
            #pragma unroll
            for (int e = 0; e < 4; ++e) {
                int m = m0 + wm * 64 + mf * 16 + lg * 4 + e;
                float v = acc[mf][nf][e] + bb;
                if (EPI == 2) {
                    if (m < M) Cf[(size_t)m * Nf + n] += v;
                } else {
                    if (m < M) {
                        float gg = 0.5f * v * (1.0f + erff(v * 0.70710678118f));
                        Cbf[(size_t)m * Nf + n] = f2bf(gg);
                    }
                }
            }
        }
    }
}

// ---------------- flash attention, MFMA bf16 ----------------
__global__ __launch_bounds__(256) void flash_mfma(
    const ushort* __restrict__ Qb, const ushort* __restrict__ Kb,
    const ushort* __restrict__ Vt, ushort* __restrict__ Ctx)
{
    __shared__ __align__(16) ushort Qs[64 * 64];
    __shared__ __align__(16) ushort Ks[64 * 64];
    __shared__ __align__(16) ushort Vs[64 * 64];
    __shared__ __align__(16) ushort Ps[64 * 64];

    int tid = threadIdx.x;
    int w = tid >> 6, l = tid & 63;
    int lr = l & 15, lg = l >> 4;
    int bh = blockIdx.y;
    int b = bh >> 2, h = bh & 3;
    int q0 = blockIdx.x * 64;
    const size_t rowbase = (size_t)b * NTOK;
    const size_t vbase = (size_t)(b * 256 + h * 64) * VSTR;

    #pragma unroll
    for (int i = 0; i < 2; ++i) {
        int id = tid + 256 * i; int r = id >> 3, c8 = id & 7;
        int qr = q0 + r; if (qr > 1024) qr = 1024;
        uint4 t = *(const uint4*)(Qb + (rowbase + qr) * 256 + h * 64 + c8 * 8);
        *(uint4*)((char*)Qs + swz16(r, c8 * 16)) = t;
    }

    f32x4 po[4] = {};
    float m_run[4] = {-1e30f, -1e30f, -1e30f, -1e30f};
    float l_run[4] = {0.f, 0.f, 0.f, 0.f};

    for (int kt = 0; kt < 17; ++kt) {
        __syncthreads();
        #pragma unroll
        for (int i = 0; i < 2; ++i) {
            int id = tid + 256 * i; int r = id >> 3, c8 = id & 7;
            int kr = kt * 64 + r; int kcl = kr > 1024 ? 1024 : kr;
            uint4 tk = *(const uint4*)(Kb + (rowbase + kcl) * 256 + h * 64 + c8 * 8);
            *(uint4*)((char*)Ks + swz16(r, c8 * 16)) = tk;
            uint4 tv = *(const uint4*)(Vt + vbase + (size_t)r * VSTR + kt * 64 + c8 * 8);
            *(uint4*)((char*)Vs + swz16(r, c8 * 16)) = tv;
        }
        __syncthreads();

        f32x4 sa[4] = {};
        #pragma unroll
        for (int ks = 0; ks < 2; ++ks) {
            bf16x8 qa = *(const bf16x8*)((char*)Qs + swz16(w * 16 + lr, ks * 64 + lg * 16));
            #pragma unroll
            for (int nf = 0; nf < 4; ++nf) {
                bf16x8 kb = *(const bf16x8*)((char*)Ks + swz16(nf * 16 + lr, ks * 64 + lg * 16));
                sa[nf] = MFMA16(qa, kb, sa[nf]);
            }
        }

        #pragma unroll
        for (int nf = 0; nf < 4; ++nf) {
            int kc = kt * 64 + nf * 16 + lr;
            bool msk = kc > 1024;
            #pragma unroll
            for (int e = 0; e < 4; ++e)
                sa[nf][e] = msk ? -1e30f : sa[nf][e] * 0.125f;
        }
        #pragma unroll
        for (int e = 0; e < 4; ++e) {
            float mx = fmaxf(fmaxf(sa[0][e], sa[1][e]), fmaxf(sa[2][e], sa[3][e]));
            #pragma unroll
            for (int t = 1; t < 16; t <<= 1) mx = fmaxf(mx, __shfl_xor(mx, t, 16));
            float mnew = fmaxf(m_run[e], mx);
            float sc = __expf(m_run[e] - mnew);
            float rs = 0.f;
            #pragma unroll
            for (int nf = 0; nf < 4; ++nf) {
                float p = __expf(sa[nf][e] - mnew);
                sa[nf][e] = p;
                rs += p;
            }
            #pragma unroll
            for (int t = 1; t < 16; t <<= 1) rs += __shfl_xor(rs, t, 16);
            l_run[e] = l_run[e] * sc + rs;
            m_run[e] = mnew;
            #pragma unroll
            for (int d = 0; d < 4; ++d) po[d][e] *= sc;
        }
        #pragma unroll
        for (int nf = 0; nf < 4; ++nf) {
            #pragma unroll
            for (int e = 0; e < 4; ++e) {
                int pr = w * 16 + lg * 4 + e;
                int pc = nf * 16 + lr;
                *(ushort*)((char*)Ps + swz16(pr, pc * 2)) = f2bf(sa[nf][e]);
            }
        }
        __syncthreads();

        #pragma unroll
        for (int ks = 0; ks < 2; ++ks) {
            bf16x8 pa = *(const bf16x8*)((char*)Ps + swz16(w * 16 + lr, ks * 64 + lg * 16));
            #pragma unroll
            for (int d = 0; d < 4; ++d) {
                bf16x8 vb = *(const bf16x8*)((char*)Vs + swz16(d * 16 + lr, ks * 64 + lg * 16));
                po[d] = MFMA16(pa, vb, po[d]);
            }
        }
    }

    #pragma unroll
    for (int e = 0; e < 4; ++e) {
        int qr = q0 + w * 16 + lg * 4 + e;
        if (qr <= 1024) {
            float inv = 1.0f / l_run[e];
            #pragma unroll
            for (int d = 0; d < 4; ++d)
                Ctx[(rowbase + qr) * 256 + h * 64 + d * 16 + lr] = f2bf(po[d][e] * inv);
        }
    }
}

// ---------------- classifier head ----------------
__global__ void head_kernel(const float* __restrict__ clsl,
                            const float* __restrict__ hw,
                            const float* __restrict__ hb,
                            float* __restrict__ out)
{
    int i = blockIdx.x * 256 + threadIdx.x;
    if (i >= BATCH * NCLS) return;
    int b = i / NCLS, c = i % NCLS;
    const float* xr = clsl + b * DMODEL;
    float acc = hb[c];
    for (int t = 0; t < DMODEL; ++t) acc += xr[t] * hw[t * NCLS + c];
    out[i] = acc;
}

// ---------------- launch ----------------
extern "C" void kernel_launch(void* const* d_in, const int* in_sizes, int n_in,
                              void* d_out, int out_size, void* d_ws, size_t ws_size,
                              hipStream_t stream) {
    const float* x      = (const float*)d_in[0];
    const float* conv_w = (const float*)d_in[1];
    const float* conv_b = (const float*)d_in[2];
    const float* cls_tok= (const float*)d_in[3];
    const float* ln1_g  = (const float*)d_in[4];
    const float* ln1_b  = (const float*)d_in[5];
    const float* wq     = (const float*)d_in[6];
    const float* bq     = (const float*)d_in[7];
    const float* wk     = (const float*)d_in[8];
    const float* bk     = (const float*)d_in[9];
    const float* wv     = (const float*)d_in[10];
    const float* bv     = (const float*)d_in[11];
    const float* wo     = (const float*)d_in[12];
    const float* bo     = (const float*)d_in[13];
    const float* ln2_g  = (const float*)d_in[14];
    const float* ln2_b  = (const float*)d_in[15];
    const float* w1     = (const float*)d_in[16];
    const float* b1     = (const float*)d_in[17];
    const float* w2     = (const float*)d_in[18];
    const float* b2     = (const float*)d_in[19];
    const float* lnf_g  = (const float*)d_in[20];
    const float* lnf_b  = (const float*)d_in[21];
    const float* head_w = (const float*)d_in[22];
    const float* head_b = (const float*)d_in[23];

    char* p = (char*)d_ws;
    float* h    = (float*)p;            p += (size_t)NROWS * DMODEL * 4;
    float* cosb = (float*)p;            p += (size_t)NTOK * 128 * 4;
    float* sinb = (float*)p;            p += (size_t)NTOK * 128 * 4;
    float* clsl = (float*)p;            p += (size_t)BATCH * DMODEL * 4;
    ushort* ybf = (ushort*)p;           p += (size_t)NROWS * DMODEL * 2;
    ushort* qbf = (ushort*)p;           p += (size_t)NROWS * DMODEL * 2;
    ushort* kbf = (ushort*)p;           p += (size_t)NROWS * DMODEL * 2;
    ushort* vT  = (ushort*)p;           p += (size_t)BATCH * 256 * VSTR * 2 + 256;
    ushort* hidbf = (ushort*)p;         p += (size_t)NROWS * HIDDEN * 2;
    ushort* wqkvT = (ushort*)p;         p += (size_t)LAYERS * 768 * DMODEL * 2;
    ushort* woT = (ushort*)p;           p += (size_t)LAYERS * DMODEL * DMODEL * 2;
    ushort* w1T = (ushort*)p;           p += (size_t)LAYERS * DMODEL * HIDDEN * 2;
    ushort* w2T = (ushort*)p;           p += (size_t)LAYERS * DMODEL * HIDDEN * 2;
    ushort* cwb = (ushort*)p;           p += (size_t)DMODEL * 768 * 2;

    // one-time prep (deterministic, every call)
    transpose_cvt_kernel<<<dim3(8, 8, LAYERS), 256, 0, stream>>>(
        wq, wqkvT, 256, 256, 65536, 196608);
    transpose_cvt_kernel<<<dim3(8, 8, LAYERS), 256, 0, stream>>>(
        wk, wqkvT + 65536, 256, 256, 65536, 196608);
    transpose_cvt_kernel<<<dim3(8, 8, LAYERS), 256, 0, stream>>>(
        wv, wqkvT + 131072, 256, 256, 65536, 196608);
    transpose_cvt_kernel<<<dim3(8, 8, LAYERS), 256, 0, stream>>>(
        wo, woT, 256, 256, 65536, 65536);
    transpose_cvt_kernel<<<dim3(32, 8, LAYERS), 256, 0, stream>>>(
        w1, w1T, 256, 1024, 262144, 262144);
    transpose_cvt_kernel<<<dim3(8, 32, LAYERS), 256, 0, stream>>>(
        w2, w2T, 1024, 256, 262144, 262144);
    rope_tab_kernel<<<(NTOK * 128 + 255) / 256, 256, 0, stream>>>(cosb, sinb);
    cls_kernel<<<BATCH, 256, 0, stream>>>(cls_tok, h);
    cvt_bf16_kernel<<<192, 256, 0, stream>>>(conv_w, cwb, DMODEL * 768);
    patch_gemm<<<dim3(4, 128), 256, 0, stream>>>(x, cwb, conv_b, h);

    const int M = NROWS;
    dim3 gqkv(12, 129), g256(4, 129), g1024(16, 129);
    int lnGrid = (M + 3) / 4;
    dim3 agrid(17, BATCH * NHEADS);

    for (int l = 0; l < LAYERS; ++l) {
        const ushort* WqkvT = wqkvT + (size_t)l * 768 * DMODEL;
        const ushort* WoT = woT + (size_t)l * DMODEL * DMODEL;
        const ushort* W1T = w1T + (size_t)l * DMODEL * HIDDEN;
        const ushort* W2T = w2T + (size_t)l * DMODEL * HIDDEN;

        ln_kernel<true><<<lnGrid, 256, 0, stream>>>(h, ybf, ln1_g + l * DMODEL,
                                                    ln1_b + l * DMODEL, M, DMODEL, DMODEL);
        gemm_qkv<<<gqkv, 256, 0, stream>>>(ybf, WqkvT, bq + l * DMODEL, bk + l * DMODEL,
                                           bv + l * DMODEL, qbf, kbf, vT, cosb, sinb, M);
        flash_mfma<<<agrid, 256, 0, stream>>>(qbf, kbf, vT, ybf);
        gemm_mfma<2><<<g256, 256, 0, stream>>>(ybf, WoT, bo + l * DMODEL, h, nullptr,
                                               M, DMODEL, DMODEL);
        ln_kernel<true><<<lnGrid, 256, 0, stream>>>(h, ybf, ln2_g + l * DMODEL,
                                                    ln2_b + l * DMODEL, M, DMODEL, DMODEL);
        gemm_mfma<3><<<g1024, 256, 0, stream>>>(ybf, W1T, b1 + l * HIDDEN, nullptr, hidbf,
                                                M, DMODEL, HIDDEN);
        gemm_mfma<2><<<g256, 256, 0, stream>>>(hidbf, W2T, b2 + l * DMODEL, h, nullptr,
                                               M, HIDDEN, DMODEL);
    }
    ln_kernel<false><<<(BATCH + 3) / 4, 256, 0, stream>>>(h, clsl, lnf_g, lnf_b,
                                                          BATCH, (long)NTOK * DMODEL, DMODEL);
    head_kernel<<<(BATCH * NCLS + 255) / 256, 256, 0, stream>>>(clsl, head_w, head_b,
                                                                (float*)d_out);
}